// Round 10
// baseline (497.287 us; speedup 1.0000x reference)
//
#include <hip/hip_runtime.h>
#include <hip/hip_bf16.h>

#define BB 2
#define NN 20000
#define EE 640000

using short8 = __attribute__((ext_vector_type(8))) short;
using f32x4  = __attribute__((ext_vector_type(4))) float;
typedef unsigned int uint;

// ---------- bf16 split: packed HW cvt (v_cvt_pk_bf16_f32), ~6 VALU ops ----------
__device__ __forceinline__ uint pack_bf16x2(float x, float y) {
    union { __hip_bfloat162 b; uint u; } c;
    c.b = __float22bfloat162_rn(make_float2(x, y));
    return c.u;
}
__device__ __forceinline__ void split2(float x, float y, uint& hi, uint& lo) {
    hi = pack_bf16x2(x, y);
    const float fx = __uint_as_float(hi << 16);
    const float fy = __uint_as_float(hi & 0xffff0000u);
    lo = pack_bf16x2(x - fx, y - fy);
}

// ---------- B-fragment load from swizzled LDS ----------
template<int KT>
__device__ __forceinline__ void loadB(const char* H, const char* L, int rowb, int emask,
                                      int li, int q, short8* bh, short8* bl) {
    const int sw = (li & emask) << 4;
    const char* rh = H + li * rowb;
    const char* rl = L + li * rowb;
#pragma unroll
    for (int kt = 0; kt < KT; ++kt) {
        const int off = (kt * 64 + q * 16) ^ sw;
        bh[kt] = *(const short8*)(rh + off);
        bl[kt] = *(const short8*)(rl + off);
    }
}

#define MFMA16(a, b, c) __builtin_amdgcn_mfma_f32_16x16x32_bf16(a, b, c, 0, 0, 0)

// ---------- register-resident-weight layer, bias from LDS ----------
// 3-term bf16x3: hi@hi + hi@lo + lo@hi (lo@lo ~2^-18 rel, dropped).
template<int KT, int MT, int WOFF>
__device__ __forceinline__ void layer_r(const short8 (&wh)[30], const short8 (&wl)[30],
                                        const float* bias, int q,
                                        const short8* bh, const short8* bl, f32x4* acc) {
#pragma unroll
    for (int mt = 0; mt < MT; ++mt) {
        const float4 bv = *(const float4*)(bias + mt * 16 + q * 4);
        acc[mt][0] = bv.x; acc[mt][1] = bv.y; acc[mt][2] = bv.z; acc[mt][3] = bv.w;
    }
#pragma unroll
    for (int kt = 0; kt < KT; ++kt) {
#pragma unroll
        for (int mt = 0; mt < MT; ++mt) acc[mt] = MFMA16(wh[WOFF + mt * KT + kt], bh[kt], acc[mt]);
#pragma unroll
        for (int mt = 0; mt < MT; ++mt) acc[mt] = MFMA16(wh[WOFF + mt * KT + kt], bl[kt], acc[mt]);
#pragma unroll
        for (int mt = 0; mt < MT; ++mt) acc[mt] = MFMA16(wl[WOFF + mt * KT + kt], bh[kt], acc[mt]);
    }
}

// ReLU + hi/lo split + packed b32 writes into swizzled LDS.
template<int MT>
__device__ __forceinline__ void store_acts(char* H, char* L, int rowb, int emask,
                                           int lane, const f32x4* acc) {
    const int li = lane & 15, q = lane >> 4;
    const int sw = (li & emask) << 4;
    char* rh = H + li * rowb;
    char* rl = L + li * rowb;
#pragma unroll
    for (int mt = 0; mt < MT; ++mt) {
        const float v0 = fmaxf(acc[mt][0], 0.f), v1 = fmaxf(acc[mt][1], 0.f);
        const float v2 = fmaxf(acc[mt][2], 0.f), v3 = fmaxf(acc[mt][3], 0.f);
        uint h01, l01, h23, l23;
        split2(v0, v1, h01, l01);
        split2(v2, v3, h23, l23);
        const int off = (mt * 32 + q * 8) ^ sw;
        *(uint*)(rh + off) = h01; *(uint*)(rh + off + 4) = h23;
        *(uint*)(rl + off) = l01; *(uint*)(rl + off + 4) = l23;
    }
}

// stage 16 input channels (float4 per lane, 4 lanes/row) into padded X0 [16][128B], emask 7
__device__ __forceinline__ void stage16(char* H, char* L, int se, int sc, float4 v) {
    uint h01, l01, h23, l23;
    split2(v.x, v.y, h01, l01);
    split2(v.z, v.w, h23, l23);
    const int sw = (se & 7) << 4;
    char* rh = H + se * 128; char* rl = L + se * 128;
    const int o = (sc * 8) ^ sw;
    *(uint*)(rh + o) = h01; *(uint*)(rh + o + 4) = h23;
    *(uint*)(rl + o) = l01; *(uint*)(rl + o + 4) = l23;
    const int oz = (32 + sc * 8) ^ sw;
    *(uint*)(rh + oz) = 0; *(uint*)(rh + oz + 4) = 0;
    *(uint*)(rl + oz) = 0; *(uint*)(rl + oz + 4) = 0;
}

// zero-pad ch16..31 of the K=32 container in an X2-shaped buffer
__device__ __forceinline__ void padX2(char* H, char* L, int li, int q) {
    const int sw = (li & 7) << 4;
    const int oz = (32 + q * 8) ^ sw;
    *(uint*)(H + li * 128 + oz) = 0; *(uint*)(H + li * 128 + oz + 4) = 0;
    *(uint*)(L + li * 128 + oz) = 0; *(uint*)(L + li * 128 + oz + 4) = 0;
}

// ---------------- edge MLP: weights in regs, TWO panels in flight per wave ----------------
template<int CSR>
__global__ __launch_bounds__(64, 1) void edge_mlp2(
    const float* __restrict__ rel, const int* __restrict__ recv, const int* __restrict__ posOf,
    const char* __restrict__ wfrag,
    const float* __restrict__ b0, const float* __restrict__ b1, const float* __restrict__ b2,
    const float* __restrict__ b3, const float* __restrict__ b4,
    float* __restrict__ outp) {
    __shared__ __align__(16) char XA0H[16 * 128], XA0L[16 * 128];
    __shared__ __align__(16) char XA1H[16 * 256], XA1L[16 * 256];
    __shared__ __align__(16) char XA2H[16 * 128], XA2L[16 * 128];
    __shared__ __align__(16) char XB0H[16 * 128], XB0L[16 * 128];
    __shared__ __align__(16) char XB1H[16 * 256], XB1L[16 * 256];
    __shared__ __align__(16) char XB2H[16 * 128], XB2L[16 * 128];
    __shared__ __align__(16) float BIAS[256];

    const int lane = threadIdx.x;
    const int li = lane & 15, q = lane >> 4;
    const int se = lane >> 2, sc = lane & 3;

    // stage biases -> LDS (layout: b0@0, b1@128, b2@192, b3@224, b4@240)
    if (lane < 32)      *(float4*)&BIAS[lane * 4] = *(const float4*)(b0 + lane * 4);
    else if (lane < 48) *(float4*)&BIAS[128 + (lane - 32) * 4] = *(const float4*)(b1 + (lane - 32) * 4);
    else if (lane < 56) *(float4*)&BIAS[192 + (lane - 48) * 4] = *(const float4*)(b2 + (lane - 48) * 4);
    else if (lane < 60) *(float4*)&BIAS[224 + (lane - 56) * 4] = *(const float4*)(b3 + (lane - 56) * 4);
    else                *(float4*)&BIAS[240 + (lane - 60) * 4] = *(const float4*)(b4 + (lane - 60) * 4);

    // all 30 weight fragments (hi+lo), 240 regs
    short8 wh[30], wl[30];
#pragma unroll
    for (int f = 0; f < 30; ++f) {
        const char* pp = wfrag + (size_t)f * 2048 + lane * 16;
        wh[f] = *(const short8*)pp;
        wl[f] = *(const short8*)(pp + 1024);
    }

    constexpr int PPB = EE / 16;         // panels per batch = 40000
    constexpr int NPAIR = BB * PPB / 2;  // 40000 pairs
    const int G = gridDim.x;

    int pr = blockIdx.x;
    if (pr >= NPAIR) return;

    float4 rvA, rvB; int ixA, ixB;
    {
        const int pA = 2 * pr;
        const int bb = pA / PPB, e0 = (pA % PPB) * 16;
        rvA = *(const float4*)(rel + ((size_t)bb * EE + e0 + se) * 16 + sc * 4);
        rvB = *(const float4*)(rel + ((size_t)bb * EE + e0 + 16 + se) * 16 + sc * 4);
        ixA = CSR ? posOf[e0 + li] : recv[e0 + li];
        ixB = CSR ? posOf[e0 + 16 + li] : recv[e0 + 16 + li];
    }

    while (true) {
        const int pA = 2 * pr;
        const int bA = pA / PPB;
        const int prn = pr + G;
        const bool more = prn < NPAIR;
        float4 rnA = {0.f, 0.f, 0.f, 0.f}, rnB = {0.f, 0.f, 0.f, 0.f};
        int jxA = 0, jxB = 0;
        if (more) {  // prefetch next pair during this pair's compute
            const int pN = 2 * prn;
            const int bb = pN / PPB, e0 = (pN % PPB) * 16;
            rnA = *(const float4*)(rel + ((size_t)bb * EE + e0 + se) * 16 + sc * 4);
            rnB = *(const float4*)(rel + ((size_t)bb * EE + e0 + 16 + se) * 16 + sc * 4);
            jxA = CSR ? posOf[e0 + li] : recv[e0 + li];
            jxB = CSR ? posOf[e0 + 16 + li] : recv[e0 + 16 + li];
        }

        stage16(XA0H, XA0L, se, sc, rvA);
        stage16(XB0H, XB0L, se, sc, rvB);

        short8 bhA[4], blA[4], bhB[4], blB[4];
        f32x4 aA[8], aB[8];

        // L1: 16->128
        loadB<1>(XA0H, XA0L, 128, 7, li, q, bhA, blA);
        loadB<1>(XB0H, XB0L, 128, 7, li, q, bhB, blB);
        layer_r<1, 8, 0>(wh, wl, BIAS + 0, q, bhA, blA, aA);
        store_acts<8>(XA1H, XA1L, 256, 7, lane, aA);
        layer_r<1, 8, 0>(wh, wl, BIAS + 0, q, bhB, blB, aB);
        store_acts<8>(XB1H, XB1L, 256, 7, lane, aB);
        // L2: 128->64
        loadB<4>(XA1H, XA1L, 256, 7, li, q, bhA, blA);
        loadB<4>(XB1H, XB1L, 256, 7, li, q, bhB, blB);
        layer_r<4, 4, 8>(wh, wl, BIAS + 128, q, bhA, blA, aA);
        store_acts<4>(XA2H, XA2L, 128, 7, lane, aA);
        layer_r<4, 4, 8>(wh, wl, BIAS + 128, q, bhB, blB, aB);
        store_acts<4>(XB2H, XB2L, 128, 7, lane, aB);
        // L3: 64->32
        loadB<2>(XA2H, XA2L, 128, 7, li, q, bhA, blA);
        loadB<2>(XB2H, XB2L, 128, 7, li, q, bhB, blB);
        layer_r<2, 2, 24>(wh, wl, BIAS + 192, q, bhA, blA, aA);
        store_acts<2>(XA0H, XA0L, 128, 7, lane, aA);
        layer_r<2, 2, 24>(wh, wl, BIAS + 192, q, bhB, blB, aB);
        store_acts<2>(XB0H, XB0L, 128, 7, lane, aB);
        // L4: 32->16
        loadB<1>(XA0H, XA0L, 128, 7, li, q, bhA, blA);
        loadB<1>(XB0H, XB0L, 128, 7, li, q, bhB, blB);
        layer_r<1, 1, 28>(wh, wl, BIAS + 224, q, bhA, blA, aA);
        store_acts<1>(XA2H, XA2L, 128, 7, lane, aA);
        layer_r<1, 1, 28>(wh, wl, BIAS + 224, q, bhB, blB, aB);
        store_acts<1>(XB2H, XB2L, 128, 7, lane, aB);
        padX2(XA2H, XA2L, li, q);
        padX2(XB2H, XB2L, li, q);
        // L5: 16->16
        loadB<1>(XA2H, XA2L, 128, 7, li, q, bhA, blA);
        loadB<1>(XB2H, XB2L, 128, 7, li, q, bhB, blB);
        layer_r<1, 1, 29>(wh, wl, BIAS + 240, q, bhA, blA, aA);
        layer_r<1, 1, 29>(wh, wl, BIAS + 240, q, bhB, blB, aB);

        if (CSR) {
            float4 vA, vB;
            vA.x = aA[0][0]; vA.y = aA[0][1]; vA.z = aA[0][2]; vA.w = aA[0][3];
            vB.x = aB[0][0]; vB.y = aB[0][1]; vB.z = aB[0][2]; vB.w = aB[0][3];
            *(float4*)(outp + ((size_t)bA * EE + ixA) * 16 + q * 4) = vA;
            *(float4*)(outp + ((size_t)bA * EE + ixB) * 16 + q * 4) = vB;
        } else {
            float* dA = outp + ((size_t)bA * NN + ixA) * 16 + q * 4;
            atomicAdd(dA + 0, aA[0][0]); atomicAdd(dA + 1, aA[0][1]);
            atomicAdd(dA + 2, aA[0][2]); atomicAdd(dA + 3, aA[0][3]);
            float* dB = outp + ((size_t)bA * NN + ixB) * 16 + q * 4;
            atomicAdd(dB + 0, aB[0][0]); atomicAdd(dB + 1, aB[0][1]);
            atomicAdd(dB + 2, aB[0][2]); atomicAdd(dB + 3, aB[0][3]);
        }
        if (!more) break;
        pr = prn; rvA = rnA; rvB = rnB; ixA = jxA; ixB = jxB;
    }
}

// ---------------- node MLP: register-resident weights, FUSED CSR gather ----------------
template<int CSR>
__global__ __launch_bounds__(64, 1) void node_mlp_r(
    const float* __restrict__ dyn, const float* __restrict__ msgOrAgg,
    const int* __restrict__ start,
    const char* __restrict__ wfrag,
    const float* __restrict__ b0, const float* __restrict__ b1, const float* __restrict__ b2,
    const float* __restrict__ b3, const float* __restrict__ b4,
    float* __restrict__ out) {
    __shared__ __align__(16) char XH0[16 * 128], XL0[16 * 128];
    __shared__ __align__(16) char XH1[16 * 256], XL1[16 * 256];
    __shared__ __align__(16) char XH2[16 * 128], XL2[16 * 128];
    __shared__ __align__(16) float BIAS[256];

    const int lane = threadIdx.x;
    const int li = lane & 15, q = lane >> 4;
    const int n4 = lane >> 2, p4 = lane & 3;

    if (lane < 32)      *(float4*)&BIAS[lane * 4] = *(const float4*)(b0 + lane * 4);
    else if (lane < 48) *(float4*)&BIAS[128 + (lane - 32) * 4] = *(const float4*)(b1 + (lane - 32) * 4);
    else if (lane < 56) *(float4*)&BIAS[192 + (lane - 48) * 4] = *(const float4*)(b2 + (lane - 48) * 4);
    else if (lane < 60) *(float4*)&BIAS[224 + (lane - 56) * 4] = *(const float4*)(b3 + (lane - 56) * 4);
    else if (lane == 60) *(float4*)&BIAS[240] = *(const float4*)(b4);
    else if (lane == 61) { BIAS[244] = b4[4]; BIAS[245] = b4[5]; BIAS[246] = 0.f; BIAS[247] = 0.f; }
    else { BIAS[248 + (lane - 62) * 4] = 0.f; BIAS[249 + (lane - 62) * 4] = 0.f;
           BIAS[250 + (lane - 62) * 4] = 0.f; BIAS[251 + (lane - 62) * 4] = 0.f; }

    short8 wh[30], wl[30];
#pragma unroll
    for (int f = 0; f < 30; ++f) {
        const char* pp = wfrag + 61440 + (size_t)f * 2048 + lane * 16;
        wh[f] = *(const short8*)pp;
        wl[f] = *(const short8*)(pp + 1024);
    }

    // agg-channel slots this lane needs (see staging layout below)
    const int co0 = (p4 < 3) ? 2 + 4 * p4 : 0;
    const int co1 = (p4 < 3) ? 4 + 4 * p4 : 14;

    constexpr int NPN = BB * (NN / 16);  // 2500
    for (int p = blockIdx.x; p < NPN; p += gridDim.x) {
        const int b = p / (NN / 16);
        const int ng0 = (p % (NN / 16)) * 16;
        const int gn = ng0 + n4;

        float g0, g1, g2, g3;
        if (CSR) {
            g0 = g1 = g2 = g3 = 0.f;
            const int s = start[gn], e = start[gn + 1];
            const float* mb = msgOrAgg + (size_t)b * EE * 16;
            for (int i = s; i < e; ++i) {
                const float* mp = mb + (size_t)i * 16;
                const float2 u = *(const float2*)(mp + co0);
                const float2 v = *(const float2*)(mp + co1);
                g0 += u.x; g1 += u.y; g2 += v.x; g3 += v.y;
            }
        } else {
            const size_t abase = ((size_t)b * NN + gn) * 16;
            const float2 u = *(const float2*)(msgOrAgg + abase + co0);
            const float2 v = *(const float2*)(msgOrAgg + abase + co1);
            g0 = u.x; g1 = u.y; g2 = v.x; g3 = v.y;
        }

        {   // stage concat(dyn[14], agg[16]) -> X0 [16 nodes][32 ch container]
            const size_t dbase = ((size_t)b * NN + gn) * 14;
            float qa0, qa1, qa2, qa3, qb0, qb1, qb2, qb3;
            if (p4 < 3) {
                const float2 u = *(const float2*)(dyn + dbase + 4 * p4);
                const float2 w = *(const float2*)(dyn + dbase + 4 * p4 + 2);
                qa0 = u.x; qa1 = u.y; qa2 = w.x; qa3 = w.y;
                qb0 = g0; qb1 = g1; qb2 = g2; qb3 = g3;
            } else {
                const float2 u = *(const float2*)(dyn + dbase + 12);
                qa0 = u.x; qa1 = u.y; qa2 = g0; qa3 = g1;
                qb0 = g2; qb1 = g3; qb2 = 0.f; qb3 = 0.f;
            }
            const int sw = (n4 & 7) << 4;
            char* rh = XH0 + n4 * 128; char* rl = XL0 + n4 * 128;
            uint h01, l01, h23, l23;
            split2(qa0, qa1, h01, l01);
            split2(qa2, qa3, h23, l23);
            const int o = (p4 * 8) ^ sw;
            *(uint*)(rh + o) = h01; *(uint*)(rh + o + 4) = h23;
            *(uint*)(rl + o) = l01; *(uint*)(rl + o + 4) = l23;
            split2(qb0, qb1, h01, l01);
            split2(qb2, qb3, h23, l23);
            const int o2 = (32 + p4 * 8) ^ sw;
            *(uint*)(rh + o2) = h01; *(uint*)(rh + o2 + 4) = h23;
            *(uint*)(rl + o2) = l01; *(uint*)(rl + o2 + 4) = l23;
        }
        short8 bh[4], bl[4];
        f32x4 acc[8];

        loadB<1>(XH0, XL0, 128, 7, li, q, bh, bl);
        layer_r<1, 8, 0>(wh, wl, BIAS + 0, q, bh, bl, acc);
        store_acts<8>(XH1, XL1, 256, 7, lane, acc);

        loadB<4>(XH1, XL1, 256, 7, li, q, bh, bl);
        layer_r<4, 4, 8>(wh, wl, BIAS + 128, q, bh, bl, acc);
        store_acts<4>(XH2, XL2, 128, 7, lane, acc);

        loadB<2>(XH2, XL2, 128, 7, li, q, bh, bl);
        layer_r<2, 2, 24>(wh, wl, BIAS + 192, q, bh, bl, acc);
        store_acts<2>(XH0, XL0, 128, 7, lane, acc);

        loadB<1>(XH0, XL0, 128, 7, li, q, bh, bl);
        layer_r<1, 1, 28>(wh, wl, BIAS + 224, q, bh, bl, acc);
        store_acts<1>(XH2, XL2, 128, 7, lane, acc);
        padX2(XH2, XL2, li, q);

        loadB<1>(XH2, XL2, 128, 7, li, q, bh, bl);
        layer_r<1, 1, 29>(wh, wl, BIAS + 240, q, bh, bl, acc);

        const int on = ng0 + li;
#pragma unroll
        for (int r = 0; r < 4; ++r) {
            const int ch = q * 4 + r;
            if (ch < 6) out[((size_t)b * NN + on) * 6 + ch] = acc[0][r];
        }
    }
}

// ---------------- weight prep: pack hi/lo bf16 A-fragments ----------------
__global__ __launch_bounds__(64) void wprep(
    const float* w0f, const float* w1f, const float* w2f, const float* w3f, const float* w4f,
    const float* w0d, const float* w1d, const float* w2d, const float* w3d, const float* w4d,
    char* __restrict__ wfrag) {
    const int bid = blockIdx.x;  // 0..59
    const int lane = threadIdx.x;
    const int net = bid / 30;
    const int r = bid % 30;
    int l, base;
    if (r < 8)       { l = 0; base = 0; }
    else if (r < 24) { l = 1; base = 8; }
    else if (r < 28) { l = 2; base = 24; }
    else if (r < 29) { l = 3; base = 28; }
    else             { l = 4; base = 29; }
    const int KTs[5] = {1, 4, 2, 1, 1};
    const int Krf[5] = {16, 128, 64, 32, 16};
    const int Krd[5] = {30, 128, 64, 32, 16};
    const int Ncf[5] = {128, 64, 32, 16, 16};
    const int Ncd[5] = {128, 64, 32, 16, 6};
    const float* Wf[5] = {w0f, w1f, w2f, w3f, w4f};
    const float* Wd[5] = {w0d, w1d, w2d, w3d, w4d};
    const int KT = KTs[l];
    const int idx = r - base;
    const int mt = idx / KT, kt = idx % KT;
    const int Kreal = net ? Krd[l] : Krf[l];
    const int Ncol  = net ? Ncd[l] : Ncf[l];
    const float* W  = net ? Wd[l] : Wf[l];
    const int ch = mt * 16 + (lane & 15);
    uint hi[4], lo[4];
#pragma unroll
    for (int t = 0; t < 4; ++t) {
        float x = 0.f, y = 0.f;
        const int k0 = kt * 32 + (lane >> 4) * 8 + 2 * t;
        if (k0 < Kreal && ch < Ncol) x = W[(size_t)k0 * Ncol + ch];
        if (k0 + 1 < Kreal && ch < Ncol) y = W[(size_t)(k0 + 1) * Ncol + ch];
        split2(x, y, hi[t], lo[t]);
    }
    uint4 H; H.x = hi[0]; H.y = hi[1]; H.z = hi[2]; H.w = hi[3];
    uint4 L; L.x = lo[0]; L.y = lo[1]; L.z = lo[2]; L.w = lo[3];
    *(uint4*)(wfrag + (size_t)bid * 2048 + lane * 16) = H;
    *(uint4*)(wfrag + (size_t)bid * 2048 + 1024 + lane * 16) = L;
}

// ---------------- CSR build ----------------
__global__ void count_k(const int* __restrict__ recv, int* __restrict__ counts) {
    const int e = blockIdx.x * 256 + threadIdx.x;
    if (e < EE) atomicAdd(&counts[recv[e]], 1);
}

__global__ __launch_bounds__(1024) void scan_k(const int* __restrict__ counts,
                                               int* __restrict__ start, int* __restrict__ cursor) {
    __shared__ int part[1024];
    const int t = threadIdx.x;
    const int lo = t * 20, hi = lo + 20 < NN ? lo + 20 : NN;
    int s = 0;
    for (int i = lo; i < hi; ++i) s += counts[i];
    part[t] = s;
    __syncthreads();
    for (int d = 1; d < 1024; d <<= 1) {
        int v = 0;
        if (t >= d) v = part[t - d];
        __syncthreads();
        part[t] += v;
        __syncthreads();
    }
    int run = t ? part[t - 1] : 0;
    for (int i = lo; i < hi; ++i) { start[i] = run; cursor[i] = run; run += counts[i]; }
    if (t == 0) start[NN] = EE;
}

__global__ void fill_k(const int* __restrict__ recv, int* __restrict__ cursor,
                       int* __restrict__ posOf) {
    const int e = blockIdx.x * 256 + threadIdx.x;
    if (e < EE) posOf[e] = atomicAdd(&cursor[recv[e]], 1);
}

extern "C" void kernel_launch(void* const* d_in, const int* in_sizes, int n_in,
                              void* d_out, int out_size, void* d_ws, size_t ws_size,
                              hipStream_t stream) {
    const float* dyn = (const float*)d_in[0];
    const float* rel = (const float*)d_in[1];
    const int* recv = (const int*)d_in[3];  // send (d_in[2]) unused by reference

    const float* fw[5]; const float* fb[5]; const float* dw[5]; const float* db[5];
    for (int i = 0; i < 5; ++i) {
        fw[i] = (const float*)d_in[4 + 2 * i];
        fb[i] = (const float*)d_in[5 + 2 * i];
        dw[i] = (const float*)d_in[14 + 2 * i];
        db[i] = (const float*)d_in[15 + 2 * i];
    }

    char* ws = (char*)d_ws;
    char* wfrag = ws;  // 122880 B used, padded to 131072
    const size_t MSG_OFF = 131072;
    const size_t MSG_SZ = (size_t)BB * EE * 16 * 4;          // 81,920,000
    const size_t POS_OFF = MSG_OFF + MSG_SZ;                 // 82,051,072
    const size_t CNT_OFF = POS_OFF + (size_t)EE * 4;         // 84,611,072
    const size_t CUR_OFF = CNT_OFF + (size_t)NN * 4;         // 84,691,072
    const size_t STA_OFF = CUR_OFF + (size_t)NN * 4;         // 84,771,072
    const size_t NEED = STA_OFF + 80128;                     // 84,851,200
    const bool csr = ws_size >= NEED;

    wprep<<<60, 64, 0, stream>>>(fw[0], fw[1], fw[2], fw[3], fw[4],
                                 dw[0], dw[1], dw[2], dw[3], dw[4], wfrag);

    if (csr) {
        float* msg = (float*)(ws + MSG_OFF);
        int* posOf = (int*)(ws + POS_OFF);
        int* counts = (int*)(ws + CNT_OFF);
        int* cursor = (int*)(ws + CUR_OFF);
        int* start = (int*)(ws + STA_OFF);

        hipMemsetAsync(counts, 0, (size_t)NN * 4, stream);
        count_k<<<(EE + 255) / 256, 256, 0, stream>>>(recv, counts);
        scan_k<<<1, 1024, 0, stream>>>(counts, start, cursor);
        fill_k<<<(EE + 255) / 256, 256, 0, stream>>>(recv, cursor, posOf);
        edge_mlp2<1><<<2048, 64, 0, stream>>>(
            rel, recv, posOf, wfrag, fb[0], fb[1], fb[2], fb[3], fb[4], msg);
        node_mlp_r<1><<<1024, 64, 0, stream>>>(
            dyn, msg, start, wfrag, db[0], db[1], db[2], db[3], db[4], (float*)d_out);
    } else {
        float* agg = (float*)(ws + MSG_OFF);
        hipMemsetAsync(agg, 0, (size_t)BB * NN * 16 * 4, stream);
        edge_mlp2<0><<<2048, 64, 0, stream>>>(
            rel, recv, nullptr, wfrag, fb[0], fb[1], fb[2], fb[3], fb[4], agg);
        node_mlp_r<0><<<1024, 64, 0, stream>>>(
            dyn, agg, nullptr, wfrag, db[0], db[1], db[2], db[3], db[4], (float*)d_out);
    }
}